// Round 4
// baseline (863.164 us; speedup 1.0000x reference)
//
#include <hip/hip_runtime.h>

// STATE=4096, CDIM=1024, fan_in=5121. RK4 x 4 steps = 16 aug-dynamics evals,
// each eval = 4 sequential matvecs (fwd L1, fwd L2, tangent L1, tangent L2).
// Weights: state rows transposed to column-major bf16 (Wt[col][row]) in ws;
// c-rows' contribution + bias precomputed in fp32 (cp1/cp2); t-row kept
// exact fp32 (T1/T2). Each phase kernel: load x-vec (16KB) into LDS, 8 cols
// per block (2 per wave), full dots, writer lane does the elementwise
// epilogue AND builds the next phase's x-vector.
#define N      4096
#define NC     1024
#define STEPS  4
#define TPB    256
#define NBLK   512

typedef unsigned short us8 __attribute__((ext_vector_type(8)));

__device__ __forceinline__ float bf2f(unsigned short u) {
  union { unsigned int i; float f; } v; v.i = ((unsigned int)u) << 16; return v.f;
}
__device__ __forceinline__ unsigned short f2bf(float f) {
  union { float f; unsigned int i; } v; v.f = f;
  const unsigned int u = v.i;
  return (unsigned short)((u + 0x7FFFu + ((u >> 16) & 1u)) >> 16);  // RNE
}
__device__ __forceinline__ float sigf(float x) { return 1.0f / (1.0f + __expf(-x)); }

// ---------------------------------------------------------------------------
// init: ycur=h, cp=bias, xA=sig(h), T=t-row (fp32 exact), rk=0
// ---------------------------------------------------------------------------
__global__ __launch_bounds__(TPB) void k_init(const float* __restrict__ h,
                                              const float* __restrict__ W1,
                                              const float* __restrict__ W2,
                                              const float* __restrict__ b1,
                                              const float* __restrict__ b2,
                                              float* __restrict__ ycur,
                                              float* __restrict__ cp1,
                                              float* __restrict__ cp2,
                                              float* __restrict__ xA,
                                              float* __restrict__ T1,
                                              float* __restrict__ T2,
                                              float* __restrict__ rk) {
  const int j = blockIdx.x * TPB + threadIdx.x;
  if (j < N) {
    ycur[j] = h[j];
    cp1[j] = b1[j];
    cp2[j] = b2[j];
    xA[j] = sigf(h[j]);
    T1[j] = W1[(size_t)(NC + N) * N + j];   // row 5120 (t-row)
    T2[j] = W2[(size_t)(NC + N) * N + j];
  }
  if (j < 16) rk[j] = 0.f;
}

// ---------------------------------------------------------------------------
// Transpose+convert: W state rows [NC, NC+N) fp32 row-major -> Wt[col][row]
// bf16. 64x64 LDS tiles, coalesced both ways. grid (64, 64, 2).
// ---------------------------------------------------------------------------
__global__ __launch_bounds__(TPB) void k_conv(const float* __restrict__ W1,
                                              const float* __restrict__ W2,
                                              unsigned short* __restrict__ Wt1,
                                              unsigned short* __restrict__ Wt2) {
  __shared__ float tile[64][65];
  const float* __restrict__ W = blockIdx.z ? W2 : W1;
  unsigned short* __restrict__ Wt = blockIdx.z ? Wt2 : Wt1;
  const int i0 = blockIdx.x * 64;   // state-row offset
  const int j0 = blockIdx.y * 64;   // column offset
  const int c = threadIdx.x & 63, rq = threadIdx.x >> 6;
#pragma unroll
  for (int m = 0; m < 16; ++m) {
    const int ii = (m << 2) + rq;
    tile[ii][c] = W[(size_t)(NC + i0 + ii) * N + j0 + c];
  }
  __syncthreads();
#pragma unroll
  for (int m = 0; m < 16; ++m) {
    const int jj = (m << 2) + rq;
    Wt[(size_t)(j0 + jj) * N + i0 + c] = f2bf(tile[c][jj]);
  }
}

// ---------------------------------------------------------------------------
// cp += c @ W[0:NC]  (fp32, once). grid (16, 8, 2), block 256.
// ---------------------------------------------------------------------------
__global__ __launch_bounds__(TPB) void k_cpart(const float* __restrict__ W1,
                                               const float* __restrict__ W2,
                                               const float* __restrict__ c,
                                               float* __restrict__ cp1,
                                               float* __restrict__ cp2) {
  const float* __restrict__ W = blockIdx.z ? W2 : W1;
  float* __restrict__ cp = blockIdx.z ? cp2 : cp1;
  __shared__ float xs[128];
  __shared__ float red[8][256];
  const int tid = threadIdx.x;
  const int cb = blockIdx.x, rc = blockIdx.y;
  const int r0 = rc * 128;
  if (tid < 128) xs[tid] = c[r0 + tid];
  __syncthreads();
  const int cg = tid & 31, rg = tid >> 5;
  const float* __restrict__ wbase = W + (size_t)r0 * N + cb * 256 + cg * 8;
  float a[8] = {0,0,0,0,0,0,0,0};
#pragma unroll
  for (int k = 0; k < 16; ++k) {
    const int r = rg + (k << 3);
    const float xv = xs[r];
    const float4 wa = *reinterpret_cast<const float4*>(wbase + (size_t)r * N);
    const float4 wb = *reinterpret_cast<const float4*>(wbase + (size_t)r * N + 4);
    a[0] = fmaf(wa.x, xv, a[0]); a[1] = fmaf(wa.y, xv, a[1]);
    a[2] = fmaf(wa.z, xv, a[2]); a[3] = fmaf(wa.w, xv, a[3]);
    a[4] = fmaf(wb.x, xv, a[4]); a[5] = fmaf(wb.y, xv, a[5]);
    a[6] = fmaf(wb.z, xv, a[6]); a[7] = fmaf(wb.w, xv, a[7]);
  }
#pragma unroll
  for (int e = 0; e < 8; ++e) red[rg][cg * 8 + e] = a[e];
  __syncthreads();
  float ssum = 0.f;
#pragma unroll
  for (int g = 0; g < 8; ++g) ssum += red[g][tid];
  atomicAdd(&cp[cb * 256 + tid], ssum);
}

// ---------------------------------------------------------------------------
// One matvec phase over column-major bf16 weights.
// modes: 0=P1 (u1; xnext=sig(u1))
//        1=P2 (f; fcur=f; xnext=s0(1-s0)*f with s0=old xout)
//        2=P3 (du1; xnext=s1(1-s1)*du1 with s1=old xout)
//        3=P4 (df; rk+=df^2; RK bookkeeping; xnext=sig(ystage_next))
// ---------------------------------------------------------------------------
__global__ __launch_bounds__(TPB) void k_phase(
    int mode,
    const unsigned short* __restrict__ Wt,
    const float* __restrict__ T,
    const float* __restrict__ cp,
    const float* __restrict__ xin,
    float* __restrict__ xout,
    float* __restrict__ fbuf,
    const float* __restrict__ tptr,
    float* __restrict__ ycur,
    float* __restrict__ ksum,
    float* __restrict__ rk,
    int rkIdx, int s, float csvn, float tA, float tB) {
  __shared__ float xs[N];
  __shared__ float red[4];
  const int tid = threadIdx.x;
#pragma unroll
  for (int q = 0; q < 4; ++q)
    reinterpret_cast<float4*>(xs)[q * 256 + tid] =
        reinterpret_cast<const float4*>(xin)[q * 256 + tid];
  __syncthreads();

  const int w = tid >> 6, l = tid & 63;
  const int j0 = blockIdx.x * 8 + w * 2;
  const unsigned short* __restrict__ w0 = Wt + (size_t)j0 * N;
  const unsigned short* __restrict__ w1 = w0 + N;
  float a0 = 0.f, a1 = 0.f;
#pragma unroll
  for (int p = 0; p < 8; ++p) {
    const int off = (p << 9) + (l << 3);
    const us8 wa = *reinterpret_cast<const us8*>(w0 + off);
    const us8 wb = *reinterpret_cast<const us8*>(w1 + off);
    const float* xp = xs + off;
#pragma unroll
    for (int e = 0; e < 8; ++e) {
      a0 = fmaf(bf2f(wa[e]), xp[e], a0);
      a1 = fmaf(bf2f(wb[e]), xp[e], a1);
    }
  }
#pragma unroll
  for (int o = 32; o >= 1; o >>= 1) {
    a0 += __shfl_down(a0, o);
    a1 += __shfl_down(a1, o);
  }

  if (l == 0) {
    const float dt = tptr[0] * (1.0f / STEPS);
    const float tcoef = fmaf(tA, dt, tB);
    float v = 0.f;
    float dots[2] = {a0, a1};
#pragma unroll
    for (int e = 0; e < 2; ++e) {
      const int j = j0 + e;
      const float a = fmaf(tcoef, T[j], dots[e]);
      if (mode == 0) {                       // P1: u1
        xout[j] = sigf(a + cp[j]);
      } else if (mode == 1) {                // P2: f
        const float fv = a + cp[j];
        fbuf[j] = fv;
        const float s0 = xout[j];            // = sig(ystage), P1's input
        xout[j] = s0 * (1.f - s0) * fv;
      } else if (mode == 2) {                // P3: du1
        const float s1 = xout[j];            // = sig(u1), P2's input
        xout[j] = s1 * (1.f - s1) * a;
      } else {                               // P4: df
        v += a * a;
        const float fc = fbuf[j];
        float y = ycur[j];
        if (s == 0)      ksum[j] = fc;
        else if (s < 3)  ksum[j] = fmaf(2.f, fc, ksum[j]);
        else { y = fmaf(dt * (1.f / 6.f), ksum[j] + fc, y); ycur[j] = y; }
        xout[j] = sigf(fmaf(csvn * dt, fc, y));   // next stage's x1
      }
    }
    if (mode == 3) red[w] = v;
  }
  if (mode == 3) {
    __syncthreads();
    if (tid == 0) atomicAdd(&rk[rkIdx], red[0] + red[1] + red[2] + red[3]);
  }
}

// ---------------------------------------------------------------------------
__global__ __launch_bounds__(128) void k_fin(const float* __restrict__ ycur,
                                             float* __restrict__ out) {
  const int j = blockIdx.x * 128 + threadIdx.x;
  out[j] = ycur[j];
}

__global__ void k_out(const float* __restrict__ rk, const float* __restrict__ tptr,
                      float* __restrict__ out) {
  if (threadIdx.x == 0) {
    const float dt = tptr[0] * (1.0f / STEPS);
    float r = 0.f;
    for (int st = 0; st < STEPS; ++st)
      r += rk[4 * st] + 2.f * rk[4 * st + 1] + 2.f * rk[4 * st + 2] + rk[4 * st + 3];
    out[N] = r * (dt / 6.f) * (1.0f / N);
  }
}

// ---------------------------------------------------------------------------
extern "C" void kernel_launch(void* const* d_in, const int* in_sizes, int n_in,
                              void* d_out, int out_size, void* d_ws, size_t ws_size,
                              hipStream_t stream) {
  const float* h  = (const float*)d_in[0];
  const float* t  = (const float*)d_in[1];
  const float* c  = (const float*)d_in[2];
  const float* W1 = (const float*)d_in[3];
  const float* b1 = (const float*)d_in[4];
  const float* W2 = (const float*)d_in[5];
  const float* b2 = (const float*)d_in[6];
  float* out = (float*)d_out;

  // ws: Wt1 | Wt2 (bf16 col-major, 33.55 MB each) | fp32 vectors. ~67.3 MB
  // total; ws_size ~336 MB per harness fill evidence.
  char* ws = (char*)d_ws;
  const size_t wb = (size_t)N * N * sizeof(unsigned short);
  unsigned short* Wt1 = (unsigned short*)ws;
  unsigned short* Wt2 = (unsigned short*)(ws + wb);
  float* fp = (float*)(ws + 2 * wb);
  float* xA   = fp;
  float* xB   = xA + N;
  float* cp1  = xB + N;
  float* cp2  = cp1 + N;
  float* fbuf = cp2 + N;
  float* ycur = fbuf + N;
  float* ksum = ycur + N;
  float* T1   = ksum + N;
  float* T2   = T1 + N;
  float* rk   = T2 + N;   // 16

  k_init<<<16, TPB, 0, stream>>>(h, W1, W2, b1, b2, ycur, cp1, cp2, xA, T1, T2, rk);
  k_conv<<<dim3(64, 64, 2), TPB, 0, stream>>>(W1, W2, Wt1, Wt2);
  k_cpart<<<dim3(16, 8, 2), TPB, 0, stream>>>(W1, W2, c, cp1, cp2);

  const float csv[4] = {0.f, 0.5f, 0.5f, 1.f};
  float* xb[2] = {xA, xB};
  int xp = 0;
  for (int i = 0; i < 16; ++i) {
    const int step = i >> 2, s = i & 3;
    const float tsv = (float)step + csv[s];
    // P1: u1 = x1@W1 + cp1 + t*T1 ; x2 = sig(u1)
    k_phase<<<NBLK, TPB, 0, stream>>>(0, Wt1, T1, cp1, xb[xp], xb[xp ^ 1], fbuf,
                                      t, ycur, ksum, rk, 0, s, 0.f, tsv, 0.f);
    xp ^= 1;
    // P2: f = x2@W2 + cp2 + t*T2 ; v1 = s0'(ys)*f
    k_phase<<<NBLK, TPB, 0, stream>>>(1, Wt2, T2, cp2, xb[xp], xb[xp ^ 1], fbuf,
                                      t, ycur, ksum, rk, 0, s, 0.f, tsv, 0.f);
    xp ^= 1;
    // P3: du1 = v1@W1 + 1*T1 ; v2 = s1'(u1)*du1
    k_phase<<<NBLK, TPB, 0, stream>>>(2, Wt1, T1, nullptr, xb[xp], xb[xp ^ 1], fbuf,
                                      t, ycur, ksum, rk, 0, s, 0.f, 0.f, 1.f);
    xp ^= 1;
    // P4: df = v2@W2 + 1*T2 ; rk += df^2 ; RK bookkeeping ; x1_next
    k_phase<<<NBLK, TPB, 0, stream>>>(3, Wt2, T2, nullptr, xb[xp], xb[xp ^ 1], fbuf,
                                      t, ycur, ksum, rk, i, s, csv[(s + 1) & 3],
                                      0.f, 1.f);
    xp ^= 1;
  }
  k_fin<<<32, 128, 0, stream>>>(ycur, out);
  k_out<<<1, 64, 0, stream>>>(rk, t, out);
}